// Round 3
// baseline (859.847 us; speedup 1.0000x reference)
//
#include <hip/hip_runtime.h>

// ============================================================================
// train_model_27925877358676 — round 7: launch-count & latency pass.
//  (1) 31 -> 21 dispatches: prep megakernel (pack+cvt+transpose+zero),
//      CSR build for both layers hoisted+fused (input-only), transpose_bf16
//      folded into xpa GEMM epilogue (transposed bf16 store), write_loss и
//      memset dropped (div_rows atomics into out, zeroed in prep).
//  (2) xp1/xp2: BK=32 split-K kernel -> mfma128 z-slab split-K (K pad 8192),
//      4x fewer vmcnt drains, 256 blocks.
//  (3) csr_agg: 4-edge batched f32x2 gathers (4 loads in flight vs 1).
// ws ≈ 138.4 MB (fp32 38.4 + bf16 100.0).
// ============================================================================

typedef unsigned short ushort;
typedef __attribute__((ext_vector_type(8))) short short8;     // 8 bf16
typedef __attribute__((ext_vector_type(4))) float float4v;    // 4 fp32 acc
typedef __attribute__((ext_vector_type(4))) float f32x4;
typedef __attribute__((ext_vector_type(2))) float f32x2;
typedef __attribute__((ext_vector_type(4))) unsigned short us4;
typedef __attribute__((ext_vector_type(2))) unsigned short us2;

__device__ __forceinline__ ushort bf16_rne(float v) {
    unsigned u = __float_as_uint(v);
    u += 0x7fffu + ((u >> 16) & 1u);
    return (ushort)(u >> 16);
}
__device__ __forceinline__ float bf16_f32(ushort h) {
    return __uint_as_float((unsigned)h << 16);
}

// ---------------- workspace layout ----------------
// fp32/int region (element offsets)
constexpr long ZCNT0 = 0;          // int[8000] (zeroed in prep)
constexpr long ZCNT1 = 8000;       // int[2000] (zeroed in prep; contiguous)
constexpr long OFF0  = 10240;
constexpr long CUR0  = 18240;
constexpr long OFF1  = 26240;
constexpr long CUR1  = 28240;
constexpr long EID0  = 30240;      // int[128000]
constexpr long EID1  = 158240;     // int[32000]
constexpr long H1F   = 190240;     // f[8064*256]
constexpr long H2F   = 2254624;    // f[2048*256]
constexpr long DIVCF = 2778912;    // f[2048*512]
constexpr long XPBF  = 3827488;    // f[2048*256]
constexpr long PB2   = 4351776;    // f[4096*256]
constexpr long PART  = 5400352;    // f[4*2048*512] split-K partial slabs
constexpr long FEND  = 9594656;
// bf16 region (ushort offsets from uws)
constexpr long U_PPRB  = 0;         // [2048][8192] (cols>=8000 zero)
constexpr long U_PPR2B = 16777216;  // [2048][2048]
constexpr long U_XTB   = 20971520;  // [512][8192]  (rows>=8000 of x -> 0)
constexpr long U_XPATB = 25165824;  // [512][2048]
constexpr long U_A0    = 26214400;  // [8064][1536] = [x | agg_hi | agg_lo]
constexpr long U_A1    = 38600704;  // [2048][1024] = [h1_hi|h1_lo|agg_hi|agg_lo]
constexpr long U_ESPL  = 40697856;  // [2048][512]  = [e_hi|e_lo]
constexpr long U_XPS   = 41746432;  // [2048][1024] = [hi|lo]
constexpr long U_SPLT  = 43843584;  // [4096][512]  = [g_hi|g_lo] stacked
constexpr long U_TSPL  = 45940736;  // [4096][512]  = [t_hi|t_lo]
constexpr long U_WC0   = 48037888;  // [256][1536] [Wr0|Wl0|Wl0]
constexpr long U_WC1   = 48431104;  // [256][1024] [Wr1|Wr1|Wl1|Wl1]
constexpr long U_BD    = 48693248;  // [512][512]  [[W1|W1];[W2|W2]]
constexpr long U_WAD   = 48955392;  // [512][1024] [Wa|Wa]
constexpr long U_WBD   = 49479680;  // [256][1024] [Wb|Wb]
constexpr long U_WP1D  = 49741824;  // [256][512]  [Wp1|Wp1]
constexpr long U_WP2D  = 49872896;  // [256][512]  [Wp2|Wp2]
// end 50003968 ushorts = 100.0 MB

// ---------------------------------------------------------------------------
// mfma128: C = op(A[M,K] @ B[N,K]^T), bf16 in. BK=128 tile 128x128, LDS
// XOR-swizzle via pre-swizzled global source (linear global_load_lds dest).
// gridDim.z > 1 => split-K: slab z covers K [z*kchunk, z*kchunk+kchunk),
// plain fp32 partial store to Cf + z*M*N. Else full epilogue:
//   Cf (fp32, nullable), Cs (bf16, nullable; rows<msplit; flags&2 ->
//   [hi@col | lo@col+nsplit] else plain), Ct (bf16 transposed, flags&4).
// flags: bit0 relu, bit1 split-store, bit2 transposed-store.
// ---------------------------------------------------------------------------
__global__ __launch_bounds__(256) void mfma128(
    const ushort* __restrict__ A, const ushort* __restrict__ B,
    float* __restrict__ Cf, ushort* __restrict__ Cs, ushort* __restrict__ Ct,
    const float* __restrict__ bias, int K, int lda, int ldb, int ldc,
    int ldso, int nsplit, int msplit, int ldt, int kchunk, int flags)
{
    __shared__ ushort As[128 * 128];
    __shared__ ushort Bs[128 * 128];
    const int tid = threadIdx.x;
    const int lane = tid & 63, wave = tid >> 6;
    const int wm = (wave >> 1) * 64, wn = (wave & 1) * 64;
    const int lr = lane & 15, quad = lane >> 4;
    const int bm = blockIdx.y * 128, bn = blockIdx.x * 128;
    const int kbeg = blockIdx.z * kchunk;
    int kend = kbeg + kchunk; if (kend > K) kend = K;

    float4v acc[4][4] = {{{0.f, 0.f, 0.f, 0.f}}};

    for (int k0 = kbeg; k0 < kend; k0 += 128) {
#pragma unroll
        for (int issue = 0; issue < 8; ++issue) {
            int c = issue * 256 + tid;           // 0..2047
            int r = c >> 4, p = c & 15;
            int kk = (p ^ (r & 15)) * 8;         // pre-swizzled source column
            const ushort* ga = A + (long)(bm + r) * lda + k0 + kk;
            const ushort* gb = B + (long)(bn + r) * ldb + k0 + kk;
            __builtin_amdgcn_global_load_lds(
                (const __attribute__((address_space(1))) unsigned int*)ga,
                (__attribute__((address_space(3))) unsigned int*)&As[c * 8], 16, 0, 0);
            __builtin_amdgcn_global_load_lds(
                (const __attribute__((address_space(1))) unsigned int*)gb,
                (__attribute__((address_space(3))) unsigned int*)&Bs[c * 8], 16, 0, 0);
        }
        __syncthreads();

#pragma unroll
        for (int s = 0; s < 4; ++s) {
            short8 af[4], bf[4];
#pragma unroll
            for (int i = 0; i < 4; ++i) {
                int ra = wm + i * 16 + lr;
                af[i] = *(const short8*)&As[ra * 128 + (((s * 4 + quad) ^ (ra & 15)) * 8)];
                int rb = wn + i * 16 + lr;
                bf[i] = *(const short8*)&Bs[rb * 128 + (((s * 4 + quad) ^ (rb & 15)) * 8)];
            }
#pragma unroll
            for (int i = 0; i < 4; ++i)
#pragma unroll
                for (int j = 0; j < 4; ++j)
                    acc[i][j] = __builtin_amdgcn_mfma_f32_16x16x32_bf16(
                        af[i], bf[j], acc[i][j], 0, 0, 0);
        }
        __syncthreads();
    }

    if (gridDim.z > 1) {
        // split-K partial slab store
        float* Cz = Cf + (long)blockIdx.z * (long)(gridDim.x * 128) * (long)(gridDim.y * 128);
#pragma unroll
        for (int i = 0; i < 4; ++i) {
            int row0 = bm + wm + i * 16 + quad * 4;
#pragma unroll
            for (int j = 0; j < 4; ++j) {
                int col = bn + wn + j * 16 + lr;
#pragma unroll
                for (int r = 0; r < 4; ++r)
                    Cz[(long)(row0 + r) * ldc + col] = acc[i][j][r];
            }
        }
        return;
    }

#pragma unroll
    for (int i = 0; i < 4; ++i) {
        int row0 = bm + wm + i * 16 + quad * 4;
#pragma unroll
        for (int j = 0; j < 4; ++j) {
            int col = bn + wn + j * 16 + lr;
            float bv = bias ? bias[col] : 0.f;
            us4 tp;
#pragma unroll
            for (int r = 0; r < 4; ++r) {
                int row = row0 + r;
                float v = acc[i][j][r] + bv;
                if (flags & 1) v = fmaxf(v, 0.f);
                if (Cf) Cf[(long)row * ldc + col] = v;
                if (Cs && row < msplit) {
                    if (flags & 2) {
                        ushort h = bf16_rne(v);
                        Cs[(long)row * ldso + col] = h;
                        Cs[(long)row * ldso + nsplit + col] = bf16_rne(v - bf16_f32(h));
                    } else {
                        Cs[(long)row * ldso + col] = bf16_rne(v);
                    }
                }
                if (flags & 4) tp[r] = bf16_rne(v);
            }
            if (flags & 4)
                *(us4*)&Ct[(long)col * ldt + row0] = tp;
        }
    }
}

// sum S partial slabs of [2048][512] -> bf16 hi/lo split [2048][1024]
__global__ __launch_bounds__(256) void reduce_split(
    const float* __restrict__ part, ushort* __restrict__ outs, long n, int S)
{
    long i = (long)blockIdx.x * 256 + threadIdx.x;
    if (i >= n) return;
    float s = 0.f;
    for (int k = 0; k < S; ++k) s += part[(long)k * n + i];
    int r = (int)(i >> 9), c = (int)(i & 511);
    ushort h = bf16_rne(s);
    outs[(long)r * 1024 + c] = h;
    outs[(long)r * 1024 + 512 + c] = bf16_rne(s - bf16_f32(h));
}

// ---------------------------------------------------------------------------
// prep megakernel: block-range dispatch.
//  [0,2048)        cvt_ppr row b -> PPRB [2048][8192], PPR2B [2048][2048]
//  [2048,6144)     transpose_cvt x tile -> XTB [512][8192]
//  [6144,6648)     x rows -> U_A0 cols 0..511 (16 rows/block)
//  [6648,6712)     pack weights (8 sections x 8 blocks, grid-stride)
//  [6712,6752)     zero cnt0/cnt1 + out loss
// ---------------------------------------------------------------------------
__global__ __launch_bounds__(256) void prep(
    const float* __restrict__ ppr, const float* __restrict__ x,
    const float* __restrict__ Wr0, const float* __restrict__ Wl0,
    const float* __restrict__ Wr1, const float* __restrict__ Wl1,
    const float* __restrict__ W1,  const float* __restrict__ W2,
    const float* __restrict__ Wa,  const float* __restrict__ Wb,
    const float* __restrict__ Wp1, const float* __restrict__ Wp2,
    ushort* __restrict__ uws, int* __restrict__ iws, float* __restrict__ outloss)
{
    __shared__ float tsm[32][33];
    int b = blockIdx.x, t = threadIdx.x;

    if (b < 2048) {                         // ---- cvt_ppr ----
        int r = b;
        bool live = r < 2000;
        const float* row = ppr + (long)r * 8000;
        for (int c = t * 4; c < 8192; c += 1024) {
            f32x4 v = {0.f, 0.f, 0.f, 0.f};
            if (live && c < 8000) v = *(const f32x4*)(row + c);
            us4 u;
            u[0] = bf16_rne(v[0]); u[1] = bf16_rne(v[1]);
            u[2] = bf16_rne(v[2]); u[3] = bf16_rne(v[3]);
            *(us4*)&uws[U_PPRB + (long)r * 8192 + c] = u;
            if (c < 2048) {
                us4 w = u;
                if (c >= 2000) { w[0] = 0; w[1] = 0; w[2] = 0; w[3] = 0; }
                *(us4*)&uws[U_PPR2B + (long)r * 2048 + c] = w;
            }
        }
        return;
    }
    if (b < 6144) {                         // ---- transpose_cvt x -> XTB ----
        int id = b - 2048;
        int c0 = (id & 15) * 32, r0 = (id >> 4) * 32;   // r0 in [0,8192)
        int tx = t & 31, ty = t >> 5;
#pragma unroll
        for (int k = 0; k < 32; k += 8) {
            int r = r0 + ty + k;
            tsm[ty + k][tx] = (r < 8000) ? x[(long)r * 512 + c0 + tx] : 0.f;
        }
        __syncthreads();
#pragma unroll
        for (int k = 0; k < 32; k += 8) {
            int c = c0 + ty + k;
            uws[U_XTB + (long)c * 8192 + r0 + tx] = bf16_rne(tsm[tx][ty + k]);
        }
        return;
    }
    if (b < 6648) {                         // ---- x -> A0 cols 0..511 ----
        int base = (b - 6144) * 16;
#pragma unroll
        for (int rr = 0; rr < 16; ++rr) {
            int r = base + rr;
            for (int c = t; c < 512; c += 256)
                uws[U_A0 + (long)r * 1536 + c] = bf16_rne(x[(long)r * 512 + c]);
        }
        return;
    }
    if (b < 6712) {                         // ---- pack weights ----
        int b2 = b - 6648;
        int sec = b2 >> 3;
        const float *sa, *sb = nullptr; long dstoff; int N, KA, dA, KB = 0, dB = 0;
        switch (sec) {
            case 0: sa = Wr0; KA = 512; dA = 1; sb = Wl0; KB = 512; dB = 2;
                    dstoff = U_WC0; N = 256; break;
            case 1: sa = Wr1; KA = 256; dA = 2; sb = Wl1; KB = 256; dB = 2;
                    dstoff = U_WC1; N = 256; break;
            case 2: sa = W1;  KA = 256; dA = 2; dstoff = U_BD;          N = 256; break;
            case 3: sa = W2;  KA = 256; dA = 2; dstoff = U_BD + 131072; N = 256; break;
            case 4: sa = Wa;  KA = 512; dA = 2; dstoff = U_WAD;  N = 512; break;
            case 5: sa = Wb;  KA = 512; dA = 2; dstoff = U_WBD;  N = 256; break;
            case 6: sa = Wp1; KA = 256; dA = 2; dstoff = U_WP1D; N = 256; break;
            default: sa = Wp2; KA = 256; dA = 2; dstoff = U_WP2D; N = 256; break;
        }
        int kd = KA * dA + KB * dB;
        long total = (long)N * kd;
        for (long idx = (long)(b2 & 7) * 256 + t; idx < total; idx += 2048) {
            int n = (int)(idx / kd), rem = (int)(idx % kd);
            float v;
            if (rem < KA * dA) v = sa[(long)n * KA + rem % KA];
            else               v = sb[(long)n * KB + (rem - KA * dA) % KB];
            uws[dstoff + idx] = bf16_rne(v);
        }
        return;
    }
    {                                       // ---- zero cnts + loss ----
        int idx = (b - 6712) * 256 + t;
        if (idx < 10000) iws[idx] = 0;      // ZCNT0 (8000) + ZCNT1 (2000)
        if (idx == 10000) *outloss = 0.f;
    }
}

// ---------------------------------------------------------------------------
// CSR build (both layers fused; input-only)
// ---------------------------------------------------------------------------
__global__ __launch_bounds__(256) void hist_both(
    const int* __restrict__ dst0, const int* __restrict__ dst1,
    int* __restrict__ cnt0, int* __restrict__ cnt1, int E0, int E1)
{
    int e = blockIdx.x * 256 + threadIdx.x;
    if (e < E0) atomicAdd(&cnt0[dst0[e]], 1);
    else if (e < E0 + E1) atomicAdd(&cnt1[dst1[e - E0]], 1);
}

// 2 blocks: b0 scans cnt0 (n=8000), b1 scans cnt1 (n=2000). 32 elems/thread.
__global__ __launch_bounds__(256) void scan_both(
    const int* __restrict__ cnt0, int* __restrict__ off0, int* __restrict__ cur0,
    const int* __restrict__ cnt1, int* __restrict__ off1, int* __restrict__ cur1)
{
    __shared__ int tot[256];
    int b = blockIdx.x, t = threadIdx.x;
    const int* cnt = b ? cnt1 : cnt0;
    int* off = b ? off1 : off0;
    int* cur = b ? cur1 : cur0;
    int n = b ? 2000 : 8000;
    int base = t * 32;
    int loc[32];
    int s = 0;
#pragma unroll
    for (int j = 0; j < 32; ++j) {
        int i = base + j;
        int v = (i < n) ? cnt[i] : 0;
        loc[j] = s; s += v;
    }
    tot[t] = s;
    __syncthreads();
    for (int d = 1; d < 256; d <<= 1) {
        int v = (t >= d) ? tot[t - d] : 0;
        __syncthreads();
        tot[t] += v;
        __syncthreads();
    }
    int bsum = (t > 0) ? tot[t - 1] : 0;
#pragma unroll
    for (int j = 0; j < 32; ++j) {
        int i = base + j;
        if (i < n) { off[i] = bsum + loc[j]; cur[i] = bsum + loc[j]; }
    }
}

__global__ __launch_bounds__(256) void fill_both(
    const int* __restrict__ src0, const int* __restrict__ dst0,
    const int* __restrict__ src1, const int* __restrict__ dst1,
    int* __restrict__ cur0, int* __restrict__ cur1,
    int* __restrict__ eid0, int* __restrict__ eid1, int E0, int E1)
{
    int e = blockIdx.x * 256 + threadIdx.x;
    if (e < E0) {
        int p = atomicAdd(&cur0[dst0[e]], 1);
        eid0[p] = src0[e];
    } else if (e < E0 + E1) {
        int e1 = e - E0;
        int p = atomicAdd(&cur1[dst1[e1]], 1);
        eid1[p] = src1[e1];
    }
}

// ---------------------------------------------------------------------------
// layer-0 gather-mean: D=512, gathers fp32 x rows, 4-edge batched f32x2.
// writes bf16 [hi|lo] into A0 row d at cols [512..1024) / [1024..1536).
// ---------------------------------------------------------------------------
__global__ __launch_bounds__(256) void csr_agg0(
    const float* __restrict__ x, const int* __restrict__ eid,
    const int* __restrict__ off, const int* __restrict__ cnt,
    ushort* __restrict__ a0)
{
    int d = blockIdx.x, t = threadIdx.x;
    f32x2 a = {0.f, 0.f};
    if (d < 8000) {
        int base = off[d], k = cnt[d];
        int j = 0;
        for (; j + 4 <= k; j += 4) {
            int e0 = eid[base + j], e1 = eid[base + j + 1];
            int e2 = eid[base + j + 2], e3 = eid[base + j + 3];
            f32x2 v0 = *(const f32x2*)&x[(long)e0 * 512 + 2 * t];
            f32x2 v1 = *(const f32x2*)&x[(long)e1 * 512 + 2 * t];
            f32x2 v2 = *(const f32x2*)&x[(long)e2 * 512 + 2 * t];
            f32x2 v3 = *(const f32x2*)&x[(long)e3 * 512 + 2 * t];
            a += v0; a += v1; a += v2; a += v3;
        }
        for (; j < k; ++j)
            a += *(const f32x2*)&x[(long)eid[base + j] * 512 + 2 * t];
        float inv = 1.f / fmaxf((float)k, 1.f);
        a[0] *= inv; a[1] *= inv;
    }
    ushort h0 = bf16_rne(a[0]), h1 = bf16_rne(a[1]);
    us2 hi = {h0, h1};
    us2 lo = {bf16_rne(a[0] - bf16_f32(h0)), bf16_rne(a[1] - bf16_f32(h1))};
    long ro = (long)d * 1536;
    *(us2*)&a0[ro + 512 + 2 * t] = hi;
    *(us2*)&a0[ro + 1024 + 2 * t] = lo;
}

// layer-1 gather-mean: D=256, gathers fp32 H1 rows. Writes into A1 row d
// at cols [512..768) hi / [768..1024) lo.
__global__ __launch_bounds__(256) void csr_agg1(
    const float* __restrict__ h, const int* __restrict__ eid,
    const int* __restrict__ off, const int* __restrict__ cnt,
    ushort* __restrict__ a1)
{
    int d = blockIdx.x, t = threadIdx.x;
    float a = 0.f;
    if (d < 2000) {
        int base = off[d], k = cnt[d];
        int j = 0;
        for (; j + 4 <= k; j += 4) {
            int e0 = eid[base + j], e1 = eid[base + j + 1];
            int e2 = eid[base + j + 2], e3 = eid[base + j + 3];
            float v0 = h[(long)e0 * 256 + t];
            float v1 = h[(long)e1 * 256 + t];
            float v2 = h[(long)e2 * 256 + t];
            float v3 = h[(long)e3 * 256 + t];
            a += v0; a += v1; a += v2; a += v3;
        }
        for (; j < k; ++j)
            a += h[(long)eid[base + j] * 256 + t];
        a *= 1.f / fmaxf((float)k, 1.f);
    }
    ushort hh = bf16_rne(a);
    long ro = (long)d * 1024;
    a1[ro + 512 + t] = hh;
    a1[ro + 768 + t] = bf16_rne(a - bf16_f32(hh));
}

// ------------------------- fused row-wise (D=256) --------------------------
__global__ __launch_bounds__(256) void logsm_l2n_split(
    const float* __restrict__ h2, ushort* __restrict__ espl,
    ushort* __restrict__ splt)
{
    __shared__ float red[256];
    int i = blockIdx.x, t = threadIdx.x;
    float v = h2[(long)i * 256 + t];
    red[t] = v;
    __syncthreads();
    for (int s = 128; s > 0; s >>= 1) {
        if (t < s) red[t] = fmaxf(red[t], red[t + s]);
        __syncthreads();
    }
    float m = red[0];
    __syncthreads();
    float e = expf(v - m);
    red[t] = e;
    __syncthreads();
    for (int s = 128; s > 0; s >>= 1) {
        if (t < s) red[t] += red[t + s];
        __syncthreads();
    }
    float eb = v - (m + logf(red[0]));
    ushort hh = bf16_rne(eb);
    espl[(long)i * 512 + t] = hh;
    espl[(long)i * 512 + 256 + t] = bf16_rne(eb - bf16_f32(hh));
    __syncthreads();
    red[t] = eb * eb;
    __syncthreads();
    for (int s = 128; s > 0; s >>= 1) {
        if (t < s) red[t] += red[t + s];
        __syncthreads();
    }
    float g = eb / fmaxf(sqrtf(red[0]), 1e-12f);
    ushort gh = bf16_rne(g);
    splt[(long)i * 512 + t] = gh;
    splt[(long)i * 512 + 256 + t] = bf16_rne(g - bf16_f32(gh));
}

__global__ __launch_bounds__(256) void l2n_split(
    const float* __restrict__ in, ushort* __restrict__ splt, int rowoff)
{
    __shared__ float red[256];
    int i = blockIdx.x, t = threadIdx.x;
    float v = in[(long)i * 256 + t];
    red[t] = v * v;
    __syncthreads();
    for (int s = 128; s > 0; s >>= 1) {
        if (t < s) red[t] += red[t + s];
        __syncthreads();
    }
    float g = v / fmaxf(sqrtf(red[0]), 1e-12f);
    ushort gh = bf16_rne(g);
    long ro = (long)(rowoff + i) * 512;
    splt[ro + t] = gh;
    splt[ro + 256 + t] = bf16_rne(g - bf16_f32(gh));
}

__global__ __launch_bounds__(256) void div_rows(
    const float* __restrict__ o1, const float* __restrict__ o2,
    float* __restrict__ loss, int ld, float scale)
{
    __shared__ float r1[256];
    __shared__ float r2[256];
    int i = blockIdx.x, t = threadIdx.x;
    float a = o1[(long)i * ld + t], b = o2[(long)i * ld + t];
    r1[t] = a * a;
    r2[t] = b * b;
    __syncthreads();
    for (int s = 128; s > 0; s >>= 1) {
        if (t < s) { r1[t] += r1[t + s]; r2[t] += r2[t + s]; }
        __syncthreads();
    }
    float na = fmaxf(sqrtf(r1[0]), 1e-12f);
    float nb = fmaxf(sqrtf(r2[0]), 1e-12f);
    __syncthreads();
    float d = a / na - b / nb;
    r1[t] = d * d;
    __syncthreads();
    for (int s = 128; s > 0; s >>= 1) {
        if (t < s) r1[t] += r1[t + s];
        __syncthreads();
    }
    if (t == 0) atomicAdd(loss, r1[0] * scale);
}

// stacked clf: block b -> half=b>>11, i=b&2047 (skip i>=2000)
__global__ __launch_bounds__(256) void clf2(
    const float* __restrict__ p, const float* __restrict__ Wc1,
    const float* __restrict__ bc1, const float* __restrict__ Wc2,
    const float* __restrict__ bc2, float* __restrict__ out)
{
    __shared__ float v[256];
    __shared__ float hsum[32];
    int b = blockIdx.x, t = threadIdx.x;
    int half = b >> 11, i = b & 2047;
    if (i >= 2000) return;
    v[t] = p[(long)b * 256 + t];
    __syncthreads();
    if (t < 32) {
        float s = bc1[t];
        const float* w = Wc1 + (long)t * 256;
        for (int k = 0; k < 256; ++k) s += v[k] * w[k];
        s = fmaxf(s, 0.f);
        hsum[t] = s * Wc2[t];
    }
    __syncthreads();
    if (t == 0) {
        float s = bc2[0];
        for (int k = 0; k < 32; ++k) s += hsum[k];
        out[(long)i * 2 + half] = s;
    }
}

// ---------------------------------------------------------------------------
extern "C" void kernel_launch(void* const* d_in, const int* in_sizes, int n_in,
                              void* d_out, int out_size, void* d_ws, size_t ws_size,
                              hipStream_t stream)
{
    constexpr int N2 = 2000;

    const float* x   = (const float*)d_in[0];
    const float* ppr = (const float*)d_in[1];
    const int* src0  = (const int*)d_in[2];
    const int* dst0  = (const int*)d_in[3];
    const int* src1  = (const int*)d_in[4];
    const int* dst1  = (const int*)d_in[5];
    const float* Wl0 = (const float*)d_in[8];
    const float* bl0 = (const float*)d_in[9];
    const float* Wr0 = (const float*)d_in[10];
    const float* Wl1 = (const float*)d_in[11];
    const float* bl1 = (const float*)d_in[12];
    const float* Wr1 = (const float*)d_in[13];
    const float* Wa  = (const float*)d_in[14];
    const float* ba  = (const float*)d_in[15];
    const float* Wb  = (const float*)d_in[16];
    const float* bb  = (const float*)d_in[17];
    const float* W1  = (const float*)d_in[18];
    const float* W2  = (const float*)d_in[19];
    const float* Wp1 = (const float*)d_in[20];
    const float* bp1 = (const float*)d_in[21];
    const float* Wp2 = (const float*)d_in[22];
    const float* bp2 = (const float*)d_in[23];
    const float* Wc1 = (const float*)d_in[24];
    const float* bc1 = (const float*)d_in[25];
    const float* Wc2 = (const float*)d_in[26];
    const float* bc2 = (const float*)d_in[27];

    const int E0 = in_sizes[2];
    const int E1 = in_sizes[4];

    float* out = (float*)d_out;              // [2000,2] logits + [1] loss
    float* ws  = (float*)d_ws;
    int*   iws = (int*)d_ws;
    ushort* uws = (ushort*)((char*)d_ws + FEND * sizeof(float));

    auto cdiv = [](int a, int b) { return (a + b - 1) / b; };

    // 1. prep: all conversions + weight packing + zeroing
    prep<<<6752, 256, 0, stream>>>(ppr, x, Wr0, Wl0, Wr1, Wl1, W1, W2,
                                   Wa, Wb, Wp1, Wp2, uws, iws, out + (long)N2 * 2);

    // 2-4. CSR build, both layers (input-only)
    hist_both<<<cdiv(E0 + E1, 256), 256, 0, stream>>>(
        dst0, dst1, iws + ZCNT0, iws + ZCNT1, E0, E1);
    scan_both<<<2, 256, 0, stream>>>(iws + ZCNT0, iws + OFF0, iws + CUR0,
                                     iws + ZCNT1, iws + OFF1, iws + CUR1);
    fill_both<<<cdiv(E0 + E1, 256), 256, 0, stream>>>(
        src0, dst0, src1, dst1, iws + CUR0, iws + CUR1,
        iws + EID0, iws + EID1, E0, E1);

    // 5-6. SAGE layer 0
    csr_agg0<<<8064, 256, 0, stream>>>(x, iws + EID0, iws + OFF0, iws + ZCNT0,
                                       uws + U_A0);
    mfma128<<<dim3(2, 63), 256, 0, stream>>>(
        uws + U_A0, uws + U_WC0, ws + H1F, uws + U_A1, nullptr, bl0,
        1536, 1536, 1536, 256, 1024, 256, 2048, 0, 1536, 3);

    // 7-8. SAGE layer 1
    csr_agg1<<<2048, 256, 0, stream>>>(ws + H1F, iws + EID1, iws + OFF1,
                                       iws + ZCNT1, uws + U_A1);
    mfma128<<<dim3(2, 16), 256, 0, stream>>>(
        uws + U_A1, uws + U_WC1, ws + H2F, nullptr, nullptr, bl1,
        1024, 1024, 1024, 256, 0, 0, 0, 0, 1024, 0);

    // 9. logsoftmax + l2n + splits
    logsm_l2n_split<<<N2, 256, 0, stream>>>(ws + H2F, uws + U_ESPL, uws + U_SPLT);

    // 10-11. divergence loss (atomic straight into out[4000])
    mfma128<<<dim3(4, 16), 256, 0, stream>>>(
        uws + U_ESPL, uws + U_BD, ws + DIVCF, nullptr, nullptr, nullptr,
        512, 512, 512, 512, 0, 0, 0, 0, 512, 0);
    div_rows<<<N2, 256, 0, stream>>>(ws + DIVCF, ws + DIVCF + 256,
                                     out + (long)N2 * 2, 512, 1.0f / N2);

    // 12-14. PPR: xp1 (split-K=4, K padded 8192) -> xpa (transposed store)
    mfma128<<<dim3(4, 16, 4), 256, 0, stream>>>(
        uws + U_PPRB, uws + U_XTB, ws + PART, nullptr, nullptr, nullptr,
        8192, 8192, 8192, 512, 0, 0, 0, 0, 2048, 0);
    reduce_split<<<4096, 256, 0, stream>>>(ws + PART, uws + U_XPS, 1048576L, 4);
    mfma128<<<dim3(4, 16), 256, 0, stream>>>(
        uws + U_XPS, uws + U_WAD, nullptr, nullptr, uws + U_XPATB, ba,
        1024, 1024, 1024, 0, 0, 0, 0, 2048, 1024, 5);

    // 15-17. xp2 (split-K=2) -> xpb
    mfma128<<<dim3(4, 16, 2), 256, 0, stream>>>(
        uws + U_PPR2B, uws + U_XPATB, ws + PART, nullptr, nullptr, nullptr,
        2048, 2048, 2048, 512, 0, 0, 0, 0, 1024, 0);
    reduce_split<<<4096, 256, 0, stream>>>(ws + PART, uws + U_XPS, 1048576L, 2);
    mfma128<<<dim3(2, 16), 256, 0, stream>>>(
        uws + U_XPS, uws + U_WBD, ws + XPBF, nullptr, nullptr, bb,
        1024, 1024, 1024, 256, 0, 0, 0, 0, 1024, 0);

    // 18. g2 split into stacked rows [2048..4096)
    l2n_split<<<N2, 256, 0, stream>>>(ws + XPBF, uws + U_SPLT, 2048);

    // 19-21. stacked proj + clf
    mfma128<<<dim3(2, 32), 256, 0, stream>>>(
        uws + U_SPLT, uws + U_WP1D, nullptr, uws + U_TSPL, nullptr, bp1,
        512, 512, 512, 0, 512, 256, 4096, 0, 512, 3);
    mfma128<<<dim3(2, 32), 256, 0, stream>>>(
        uws + U_TSPL, uws + U_WP2D, ws + PB2, nullptr, nullptr, bp2,
        512, 512, 512, 256, 0, 0, 0, 0, 512, 0);
    clf2<<<4096, 256, 0, stream>>>(ws + PB2, Wc1, bc1, Wc2, bc2, out);
}

// Round 4
// 761.228 us; speedup vs baseline: 1.1296x; 1.1296x over previous
//
#include <hip/hip_runtime.h>

// ============================================================================
// train_model_27925877358676 — round 8: fix prep (178us @ 8% BW, tail-bound)
//  (1) prep reordered: zero+pack first (tail-risk), ppr 4 blocks/row (MLP),
//      x in two passes: transpose tiles -> XTB; vectorized row pass -> new
//      bf16 XB[40000][512] + A0 x-cols (us4 stores).
//  (2) csr_agg0 gathers bf16 XB (lossless, x pre-rounded to bf16): 262->131MB,
//      4-wave us8 layout (1KB/row/wave-instr), 4-edge batch, LDS reduce.
//      csr_agg1 same structure on fp32 H1.
//  (3) rest identical to round 7 (21 dispatches).
// ws ≈ 179 MB (fp32 38.4 + bf16 141.0).
// ============================================================================

typedef unsigned short ushort;
typedef __attribute__((ext_vector_type(8))) short short8;     // 8 bf16
typedef __attribute__((ext_vector_type(4))) float float4v;    // 4 fp32 acc
typedef __attribute__((ext_vector_type(4))) float f32x4;
typedef __attribute__((ext_vector_type(2))) float f32x2;
typedef __attribute__((ext_vector_type(8))) unsigned short us8;
typedef __attribute__((ext_vector_type(4))) unsigned short us4;
typedef __attribute__((ext_vector_type(2))) unsigned short us2;

__device__ __forceinline__ ushort bf16_rne(float v) {
    unsigned u = __float_as_uint(v);
    u += 0x7fffu + ((u >> 16) & 1u);
    return (ushort)(u >> 16);
}
__device__ __forceinline__ float bf16_f32(ushort h) {
    return __uint_as_float((unsigned)h << 16);
}

// ---------------- workspace layout ----------------
// fp32/int region (element offsets)
constexpr long ZCNT0 = 0;          // int[8000] (zeroed in prep)
constexpr long ZCNT1 = 8000;       // int[2000]
constexpr long OFF0  = 10240;
constexpr long CUR0  = 18240;
constexpr long OFF1  = 26240;
constexpr long CUR1  = 28240;
constexpr long EID0  = 30240;      // int[128000]
constexpr long EID1  = 158240;     // int[32000]
constexpr long H1F   = 190240;     // f[8064*256]
constexpr long H2F   = 2254624;    // f[2048*256]
constexpr long DIVCF = 2778912;    // f[2048*512]
constexpr long XPBF  = 3827488;    // f[2048*256]
constexpr long PB2   = 4351776;    // f[4096*256]
constexpr long PART  = 5400352;    // f[4*2048*512] split-K partial slabs
constexpr long FEND  = 9594656;
// bf16 region (ushort offsets from uws)
constexpr long U_PPRB  = 0;         // [2048][8192] (pad cols/rows zero)
constexpr long U_PPR2B = 16777216;  // [2048][2048]
constexpr long U_XTB   = 20971520;  // [512][8192]  (node cols >=8000 zero)
constexpr long U_XPATB = 25165824;  // [512][2048]
constexpr long U_A0    = 26214400;  // [8064][1536] = [x | agg_hi | agg_lo]
constexpr long U_A1    = 38600704;  // [2048][1024] = [h1_hi|h1_lo|agg_hi|agg_lo]
constexpr long U_ESPL  = 40697856;  // [2048][512]  = [e_hi|e_lo]
constexpr long U_XPS   = 41746432;  // [2048][1024] = [hi|lo]
constexpr long U_SPLT  = 43843584;  // [4096][512]  = [g_hi|g_lo] stacked
constexpr long U_TSPL  = 45940736;  // [4096][512]  = [t_hi|t_lo]
constexpr long U_WC0   = 48037888;  // [256][1536] [Wr0|Wl0|Wl0]
constexpr long U_WC1   = 48431104;  // [256][1024] [Wr1|Wr1|Wl1|Wl1]
constexpr long U_BD    = 48693248;  // [512][512]  [[W1|W1];[W2|W2]]
constexpr long U_WAD   = 48955392;  // [512][1024] [Wa|Wa]
constexpr long U_WBD   = 49479680;  // [256][1024] [Wb|Wb]
constexpr long U_WP1D  = 49741824;  // [256][512]  [Wp1|Wp1]
constexpr long U_WP2D  = 49872896;  // [256][512]  [Wp2|Wp2]
constexpr long U_XB    = 50003968;  // [40000][512] bf16 copy of x (exact)
// end 70483968 ushorts = 141.0 MB

// ---------------------------------------------------------------------------
// mfma128: C = op(A[M,K] @ B[N,K]^T), bf16 in. BK=128 tile 128x128, LDS
// XOR-swizzle via pre-swizzled global source (linear global_load_lds dest).
// gridDim.z > 1 => split-K slab store to Cf + z*M*N. Else epilogue:
//   Cf fp32 (nullable); Cs bf16 (rows<msplit; flags&2 -> [hi|lo@+nsplit]
//   else plain); Ct bf16 transposed (flags&4).
// flags: bit0 relu, bit1 split-store, bit2 transposed-store.
// ---------------------------------------------------------------------------
__global__ __launch_bounds__(256) void mfma128(
    const ushort* __restrict__ A, const ushort* __restrict__ B,
    float* __restrict__ Cf, ushort* __restrict__ Cs, ushort* __restrict__ Ct,
    const float* __restrict__ bias, int K, int lda, int ldb, int ldc,
    int ldso, int nsplit, int msplit, int ldt, int kchunk, int flags)
{
    __shared__ ushort As[128 * 128];
    __shared__ ushort Bs[128 * 128];
    const int tid = threadIdx.x;
    const int lane = tid & 63, wave = tid >> 6;
    const int wm = (wave >> 1) * 64, wn = (wave & 1) * 64;
    const int lr = lane & 15, quad = lane >> 4;
    const int bm = blockIdx.y * 128, bn = blockIdx.x * 128;
    const int kbeg = blockIdx.z * kchunk;
    int kend = kbeg + kchunk; if (kend > K) kend = K;

    float4v acc[4][4] = {{{0.f, 0.f, 0.f, 0.f}}};

    for (int k0 = kbeg; k0 < kend; k0 += 128) {
#pragma unroll
        for (int issue = 0; issue < 8; ++issue) {
            int c = issue * 256 + tid;           // 0..2047
            int r = c >> 4, p = c & 15;
            int kk = (p ^ (r & 15)) * 8;         // pre-swizzled source column
            const ushort* ga = A + (long)(bm + r) * lda + k0 + kk;
            const ushort* gb = B + (long)(bn + r) * ldb + k0 + kk;
            __builtin_amdgcn_global_load_lds(
                (const __attribute__((address_space(1))) unsigned int*)ga,
                (__attribute__((address_space(3))) unsigned int*)&As[c * 8], 16, 0, 0);
            __builtin_amdgcn_global_load_lds(
                (const __attribute__((address_space(1))) unsigned int*)gb,
                (__attribute__((address_space(3))) unsigned int*)&Bs[c * 8], 16, 0, 0);
        }
        __syncthreads();

#pragma unroll
        for (int s = 0; s < 4; ++s) {
            short8 af[4], bf[4];
#pragma unroll
            for (int i = 0; i < 4; ++i) {
                int ra = wm + i * 16 + lr;
                af[i] = *(const short8*)&As[ra * 128 + (((s * 4 + quad) ^ (ra & 15)) * 8)];
                int rb = wn + i * 16 + lr;
                bf[i] = *(const short8*)&Bs[rb * 128 + (((s * 4 + quad) ^ (rb & 15)) * 8)];
            }
#pragma unroll
            for (int i = 0; i < 4; ++i)
#pragma unroll
                for (int j = 0; j < 4; ++j)
                    acc[i][j] = __builtin_amdgcn_mfma_f32_16x16x32_bf16(
                        af[i], bf[j], acc[i][j], 0, 0, 0);
        }
        __syncthreads();
    }

    if (gridDim.z > 1) {
        float* Cz = Cf + (long)blockIdx.z * (long)(gridDim.x * 128) * (long)(gridDim.y * 128);
#pragma unroll
        for (int i = 0; i < 4; ++i) {
            int row0 = bm + wm + i * 16 + quad * 4;
#pragma unroll
            for (int j = 0; j < 4; ++j) {
                int col = bn + wn + j * 16 + lr;
#pragma unroll
                for (int r = 0; r < 4; ++r)
                    Cz[(long)(row0 + r) * ldc + col] = acc[i][j][r];
            }
        }
        return;
    }

#pragma unroll
    for (int i = 0; i < 4; ++i) {
        int row0 = bm + wm + i * 16 + quad * 4;
#pragma unroll
        for (int j = 0; j < 4; ++j) {
            int col = bn + wn + j * 16 + lr;
            float bv = bias ? bias[col] : 0.f;
            us4 tp;
#pragma unroll
            for (int r = 0; r < 4; ++r) {
                int row = row0 + r;
                float v = acc[i][j][r] + bv;
                if (flags & 1) v = fmaxf(v, 0.f);
                if (Cf) Cf[(long)row * ldc + col] = v;
                if (Cs && row < msplit) {
                    if (flags & 2) {
                        ushort h = bf16_rne(v);
                        Cs[(long)row * ldso + col] = h;
                        Cs[(long)row * ldso + nsplit + col] = bf16_rne(v - bf16_f32(h));
                    } else {
                        Cs[(long)row * ldso + col] = bf16_rne(v);
                    }
                }
                if (flags & 4) tp[r] = bf16_rne(v);
            }
            if (flags & 4)
                *(us4*)&Ct[(long)col * ldt + row0] = tp;
        }
    }
}

// sum S partial slabs of [2048][512] -> bf16 hi/lo split [2048][1024]
__global__ __launch_bounds__(256) void reduce_split(
    const float* __restrict__ part, ushort* __restrict__ outs, long n, int S)
{
    long i = (long)blockIdx.x * 256 + threadIdx.x;
    if (i >= n) return;
    float s = 0.f;
    for (int k = 0; k < S; ++k) s += part[(long)k * n + i];
    int r = (int)(i >> 9), c = (int)(i & 511);
    ushort h = bf16_rne(s);
    outs[(long)r * 1024 + c] = h;
    outs[(long)r * 1024 + 512 + c] = bf16_rne(s - bf16_f32(h));
}

// ---------------------------------------------------------------------------
// prep megakernel. Block ranges (tail-risk segments FIRST):
//  [0,40)           zero cnt0/cnt1 + out loss
//  [40,296)         pack weights: 8 sections x 32 blocks, x2-vectorized
//  [296,8488)       ppr: 4 blocks/row -> PPRB [2048][8192], PPR2B
//  [8488,12584)     transpose x 32x32 tiles -> XTB [512][8192]
//  [12584,13864)    x row pass: f32x4 -> XB us4 (all 40000 rows) + A0 cols
// ---------------------------------------------------------------------------
__global__ __launch_bounds__(256) void prep(
    const float* __restrict__ ppr, const float* __restrict__ x,
    const float* __restrict__ Wr0, const float* __restrict__ Wl0,
    const float* __restrict__ Wr1, const float* __restrict__ Wl1,
    const float* __restrict__ W1,  const float* __restrict__ W2,
    const float* __restrict__ Wa,  const float* __restrict__ Wb,
    const float* __restrict__ Wp1, const float* __restrict__ Wp2,
    ushort* __restrict__ uws, int* __restrict__ iws, float* __restrict__ outloss)
{
    __shared__ float tsm[32][33];
    int b = blockIdx.x, t = threadIdx.x;

    if (b < 40) {                           // ---- zero ----
        int idx = b * 256 + t;
        if (idx < 10000) iws[idx] = 0;
        if (idx == 10000) *outloss = 0.f;
        return;
    }
    if (b < 296) {                          // ---- pack weights ----
        int b2 = b - 40;
        int sec = b2 >> 5;
        const float *sa, *sb = nullptr; long dstoff; int N, KA, dA, KB = 0, dB = 0;
        switch (sec) {
            case 0: sa = Wr0; KA = 512; dA = 1; sb = Wl0; KB = 512; dB = 2;
                    dstoff = U_WC0; N = 256; break;
            case 1: sa = Wr1; KA = 256; dA = 2; sb = Wl1; KB = 256; dB = 2;
                    dstoff = U_WC1; N = 256; break;
            case 2: sa = W1;  KA = 256; dA = 2; dstoff = U_BD;          N = 256; break;
            case 3: sa = W2;  KA = 256; dA = 2; dstoff = U_BD + 131072; N = 256; break;
            case 4: sa = Wa;  KA = 512; dA = 2; dstoff = U_WAD;  N = 512; break;
            case 5: sa = Wb;  KA = 512; dA = 2; dstoff = U_WBD;  N = 256; break;
            case 6: sa = Wp1; KA = 256; dA = 2; dstoff = U_WP1D; N = 256; break;
            default: sa = Wp2; KA = 256; dA = 2; dstoff = U_WP2D; N = 256; break;
        }
        int kd = KA * dA + KB * dB;
        long totv = (long)N * kd / 2;
        for (long v = (long)(b2 & 31) * 256 + t; v < totv; v += 8192) {
            long idx = v * 2;
            int n = (int)(idx / kd), rem = (int)(idx % kd);
            f32x2 val;
            if (rem < KA * dA) {
                int sc = rem % KA;
                val = *(const f32x2*)&sa[(long)n * KA + sc];
            } else {
                int sc = (rem - KA * dA) % KB;
                val = *(const f32x2*)&sb[(long)n * KB + sc];
            }
            us2 o; o[0] = bf16_rne(val[0]); o[1] = bf16_rne(val[1]);
            *(us2*)&uws[dstoff + idx] = o;
        }
        return;
    }
    if (b < 8488) {                         // ---- ppr conversion ----
        int id = b - 296;
        int r = id >> 2, q = id & 3;        // row, col-quarter
        bool live = r < 2000;
        const float* row = ppr + (long)r * 8000;
        int cbeg = q * 2048;
#pragma unroll
        for (int pass = 0; pass < 2; ++pass) {
            int c = cbeg + pass * 1024 + t * 4;
            f32x4 v = {0.f, 0.f, 0.f, 0.f};
            if (live && c < 8000) v = *(const f32x4*)(row + c);
            us4 u;
            u[0] = bf16_rne(v[0]); u[1] = bf16_rne(v[1]);
            u[2] = bf16_rne(v[2]); u[3] = bf16_rne(v[3]);
            *(us4*)&uws[U_PPRB + (long)r * 8192 + c] = u;
            if (c < 2048) {
                us4 w = u;
                if (c >= 2000) { w[0] = 0; w[1] = 0; w[2] = 0; w[3] = 0; }
                *(us4*)&uws[U_PPR2B + (long)r * 2048 + c] = w;
            }
        }
        return;
    }
    if (b < 12584) {                        // ---- transpose x -> XTB ----
        int id = b - 8488;
        int c0 = (id & 15) * 32, r0 = (id >> 4) * 32;   // r0 in [0,8192)
        int tx = t & 31, ty = t >> 5;
#pragma unroll
        for (int k = 0; k < 32; k += 8) {
            int r = r0 + ty + k;
            tsm[ty + k][tx] = (r < 8000) ? x[(long)r * 512 + c0 + tx] : 0.f;
        }
        __syncthreads();
#pragma unroll
        for (int k = 0; k < 32; k += 8) {
            int c = c0 + ty + k;
            uws[U_XTB + (long)c * 8192 + r0 + tx] = bf16_rne(tsm[tx][ty + k]);
        }
        return;
    }
    {                                       // ---- x row pass -> XB + A0 ----
        long vi = (long)(b - 12584) * 256 + t;
        for (; vi < 5120000; vi += 327680) {
            long gidx = vi * 4;
            f32x4 v = *(const f32x4*)&x[gidx];
            us4 u;
            u[0] = bf16_rne(v[0]); u[1] = bf16_rne(v[1]);
            u[2] = bf16_rne(v[2]); u[3] = bf16_rne(v[3]);
            *(us4*)&uws[U_XB + gidx] = u;
            long row = gidx >> 9;
            if (row < 8064) {
                int col = (int)(gidx & 511);
                *(us4*)&uws[U_A0 + row * 1536 + col] = u;
            }
        }
    }
}

// ---------------------------------------------------------------------------
// CSR build (both layers fused; input-only)
// ---------------------------------------------------------------------------
__global__ __launch_bounds__(256) void hist_both(
    const int* __restrict__ dst0, const int* __restrict__ dst1,
    int* __restrict__ cnt0, int* __restrict__ cnt1, int E0, int E1)
{
    int e = blockIdx.x * 256 + threadIdx.x;
    if (e < E0) atomicAdd(&cnt0[dst0[e]], 1);
    else if (e < E0 + E1) atomicAdd(&cnt1[dst1[e - E0]], 1);
}

__global__ __launch_bounds__(256) void scan_both(
    const int* __restrict__ cnt0, int* __restrict__ off0, int* __restrict__ cur0,
    const int* __restrict__ cnt1, int* __restrict__ off1, int* __restrict__ cur1)
{
    __shared__ int tot[256];
    int b = blockIdx.x, t = threadIdx.x;
    const int* cnt = b ? cnt1 : cnt0;
    int* off = b ? off1 : off0;
    int* cur = b ? cur1 : cur0;
    int n = b ? 2000 : 8000;
    int base = t * 32;
    int loc[32];
    int s = 0;
#pragma unroll
    for (int j = 0; j < 32; ++j) {
        int i = base + j;
        int v = (i < n) ? cnt[i] : 0;
        loc[j] = s; s += v;
    }
    tot[t] = s;
    __syncthreads();
    for (int d = 1; d < 256; d <<= 1) {
        int v = (t >= d) ? tot[t - d] : 0;
        __syncthreads();
        tot[t] += v;
        __syncthreads();
    }
    int bsum = (t > 0) ? tot[t - 1] : 0;
#pragma unroll
    for (int j = 0; j < 32; ++j) {
        int i = base + j;
        if (i < n) { off[i] = bsum + loc[j]; cur[i] = bsum + loc[j]; }
    }
}

__global__ __launch_bounds__(256) void fill_both(
    const int* __restrict__ src0, const int* __restrict__ dst0,
    const int* __restrict__ src1, const int* __restrict__ dst1,
    int* __restrict__ cur0, int* __restrict__ cur1,
    int* __restrict__ eid0, int* __restrict__ eid1, int E0, int E1)
{
    int e = blockIdx.x * 256 + threadIdx.x;
    if (e < E0) {
        int p = atomicAdd(&cur0[dst0[e]], 1);
        eid0[p] = src0[e];
    } else if (e < E0 + E1) {
        int e1 = e - E0;
        int p = atomicAdd(&cur1[dst1[e1]], 1);
        eid1[p] = src1[e1];
    }
}

// ---------------------------------------------------------------------------
// layer-0 gather-mean from bf16 XB (exact): 4 waves split the edge list,
// us8 loads (16B/lane x 64 lanes = full 1KB row per wave-instr), 4-edge
// batch, LDS cross-wave reduce. Writes A0 [hi|lo] cols [512..1536).
// ---------------------------------------------------------------------------
__global__ __launch_bounds__(256) void csr_agg0(
    const ushort* __restrict__ xb, const int* __restrict__ eid,
    const int* __restrict__ off, const int* __restrict__ cnt,
    ushort* __restrict__ a0)
{
    __shared__ float part[4][512];
    int d = blockIdx.x, t = threadIdx.x;
    int w = t >> 6, lane = t & 63;
    int k = (d < 8000) ? cnt[d] : 0;
    int base = (d < 8000) ? off[d] : 0;
    float s[8] = {0.f, 0.f, 0.f, 0.f, 0.f, 0.f, 0.f, 0.f};
    int co = lane * 8;
    int j = w;
    for (; j + 12 < k; j += 16) {
        int e0 = eid[base + j],     e1 = eid[base + j + 4];
        int e2 = eid[base + j + 8], e3 = eid[base + j + 12];
        us8 v0 = *(const us8*)&xb[(long)e0 * 512 + co];
        us8 v1 = *(const us8*)&xb[(long)e1 * 512 + co];
        us8 v2 = *(const us8*)&xb[(long)e2 * 512 + co];
        us8 v3 = *(const us8*)&xb[(long)e3 * 512 + co];
#pragma unroll
        for (int q = 0; q < 8; ++q)
            s[q] += bf16_f32(v0[q]) + bf16_f32(v1[q]) +
                    bf16_f32(v2[q]) + bf16_f32(v3[q]);
    }
    for (; j < k; j += 4) {
        us8 v = *(const us8*)&xb[(long)eid[base + j] * 512 + co];
#pragma unroll
        for (int q = 0; q < 8; ++q) s[q] += bf16_f32(v[q]);
    }
#pragma unroll
    for (int q = 0; q < 8; ++q) part[w][co + q] = s[q];
    __syncthreads();
    float inv = 1.f / fmaxf((float)k, 1.f);
    long ro = (long)d * 1536;
#pragma unroll
    for (int h = 0; h < 2; ++h) {
        int c = 2 * t + h;
        float a = (part[0][c] + part[1][c] + part[2][c] + part[3][c]) * inv;
        ushort hi = bf16_rne(a);
        a0[ro + 512 + c] = hi;
        a0[ro + 1024 + c] = bf16_rne(a - bf16_f32(hi));
    }
}

// layer-1 gather-mean from fp32 H1 (not bf16-exact): same 4-wave structure,
// f32x4 loads (16B/lane = full 1KB row). Writes A1 [hi|lo] cols [512..1024).
__global__ __launch_bounds__(256) void csr_agg1(
    const float* __restrict__ h, const int* __restrict__ eid,
    const int* __restrict__ off, const int* __restrict__ cnt,
    ushort* __restrict__ a1)
{
    __shared__ float part[4][256];
    int d = blockIdx.x, t = threadIdx.x;
    int w = t >> 6, lane = t & 63;
    int k = (d < 2000) ? cnt[d] : 0;
    int base = (d < 2000) ? off[d] : 0;
    f32x4 s = {0.f, 0.f, 0.f, 0.f};
    int co = lane * 4;
    int j = w;
    for (; j + 12 < k; j += 16) {
        int e0 = eid[base + j],     e1 = eid[base + j + 4];
        int e2 = eid[base + j + 8], e3 = eid[base + j + 12];
        f32x4 v0 = *(const f32x4*)&h[(long)e0 * 256 + co];
        f32x4 v1 = *(const f32x4*)&h[(long)e1 * 256 + co];
        f32x4 v2 = *(const f32x4*)&h[(long)e2 * 256 + co];
        f32x4 v3 = *(const f32x4*)&h[(long)e3 * 256 + co];
        s += v0; s += v1; s += v2; s += v3;
    }
    for (; j < k; j += 4)
        s += *(const f32x4*)&h[(long)eid[base + j] * 256 + co];
#pragma unroll
    for (int q = 0; q < 4; ++q) part[w][co + q] = s[q];
    __syncthreads();
    float inv = 1.f / fmaxf((float)k, 1.f);
    float a = (part[0][t] + part[1][t] + part[2][t] + part[3][t]) * inv;
    ushort hi = bf16_rne(a);
    long ro = (long)d * 1024;
    a1[ro + 512 + t] = hi;
    a1[ro + 768 + t] = bf16_rne(a - bf16_f32(hi));
}

// ------------------------- fused row-wise (D=256) --------------------------
__global__ __launch_bounds__(256) void logsm_l2n_split(
    const float* __restrict__ h2, ushort* __restrict__ espl,
    ushort* __restrict__ splt)
{
    __shared__ float red[256];
    int i = blockIdx.x, t = threadIdx.x;
    float v = h2[(long)i * 256 + t];
    red[t] = v;
    __syncthreads();
    for (int s = 128; s > 0; s >>= 1) {
        if (t < s) red[t] = fmaxf(red[t], red[t + s]);
        __syncthreads();
    }
    float m = red[0];
    __syncthreads();
    float e = expf(v - m);
    red[t] = e;
    __syncthreads();
    for (int s = 128; s > 0; s >>= 1) {
        if (t < s) red[t] += red[t + s];
        __syncthreads();
    }
    float eb = v - (m + logf(red[0]));
    ushort hh = bf16_rne(eb);
    espl[(long)i * 512 + t] = hh;
    espl[(long)i * 512 + 256 + t] = bf16_rne(eb - bf16_f32(hh));
    __syncthreads();
    red[t] = eb * eb;
    __syncthreads();
    for (int s = 128; s > 0; s >>= 1) {
        if (t < s) red[t] += red[t + s];
        __syncthreads();
    }
    float g = eb / fmaxf(sqrtf(red[0]), 1e-12f);
    ushort gh = bf16_rne(g);
    splt[(long)i * 512 + t] = gh;
    splt[(long)i * 512 + 256 + t] = bf16_rne(g - bf16_f32(gh));
}

__global__ __launch_bounds__(256) void l2n_split(
    const float* __restrict__ in, ushort* __restrict__ splt, int rowoff)
{
    __shared__ float red[256];
    int i = blockIdx.x, t = threadIdx.x;
    float v = in[(long)i * 256 + t];
    red[t] = v * v;
    __syncthreads();
    for (int s = 128; s > 0; s >>= 1) {
        if (t < s) red[t] += red[t + s];
        __syncthreads();
    }
    float g = v / fmaxf(sqrtf(red[0]), 1e-12f);
    ushort gh = bf16_rne(g);
    long ro = (long)(rowoff + i) * 512;
    splt[ro + t] = gh;
    splt[ro + 256 + t] = bf16_rne(g - bf16_f32(gh));
}

__global__ __launch_bounds__(256) void div_rows(
    const float* __restrict__ o1, const float* __restrict__ o2,
    float* __restrict__ loss, int ld, float scale)
{
    __shared__ float r1[256];
    __shared__ float r2[256];
    int i = blockIdx.x, t = threadIdx.x;
    float a = o1[(long)i * ld + t], b = o2[(long)i * ld + t];
    r1[t] = a * a;
    r2[t] = b * b;
    __syncthreads();
    for (int s = 128; s > 0; s >>= 1) {
        if (t < s) { r1[t] += r1[t + s]; r2[t] += r2[t + s]; }
        __syncthreads();
    }
    float na = fmaxf(sqrtf(r1[0]), 1e-12f);
    float nb = fmaxf(sqrtf(r2[0]), 1e-12f);
    __syncthreads();
    float d = a / na - b / nb;
    r1[t] = d * d;
    __syncthreads();
    for (int s = 128; s > 0; s >>= 1) {
        if (t < s) r1[t] += r1[t + s];
        __syncthreads();
    }
    if (t == 0) atomicAdd(loss, r1[0] * scale);
}

// stacked clf: block b -> half=b>>11, i=b&2047 (skip i>=2000)
__global__ __launch_bounds__(256) void clf2(
    const float* __restrict__ p, const float* __restrict__ Wc1,
    const float* __restrict__ bc1, const float* __restrict__ Wc2,
    const float* __restrict__ bc2, float* __restrict__ out)
{
    __shared__ float v[256];
    __shared__ float hsum[32];
    int b = blockIdx.x, t = threadIdx.x;
    int half = b >> 11, i = b & 2047;
    if (i >= 2000) return;
    v[t] = p[(long)b * 256 + t];
    __syncthreads();
    if (t < 32) {
        float s = bc1[t];
        const float* w = Wc1 + (long)t * 256;
        for (int k = 0; k < 256; ++k) s += v[k] * w[k];
        s = fmaxf(s, 0.f);
        hsum[t] = s * Wc2[t];
    }
    __syncthreads();
    if (t == 0) {
        float s = bc2[0];
        for (int k = 0; k < 32; ++k) s += hsum[k];
        out[(long)i * 2 + half] = s;
    }
}

// ---------------------------------------------------------------------------
extern "C" void kernel_launch(void* const* d_in, const int* in_sizes, int n_in,
                              void* d_out, int out_size, void* d_ws, size_t ws_size,
                              hipStream_t stream)
{
    constexpr int N2 = 2000;

    const float* x   = (const float*)d_in[0];
    const float* ppr = (const float*)d_in[1];
    const int* src0  = (const int*)d_in[2];
    const int* dst0  = (const int*)d_in[3];
    const int* src1  = (const int*)d_in[4];
    const int* dst1  = (const int*)d_in[5];
    const float* Wl0 = (const float*)d_in[8];
    const float* bl0 = (const float*)d_in[9];
    const float* Wr0 = (const float*)d_in[10];
    const float* Wl1 = (const float*)d_in[11];
    const float* bl1 = (const float*)d_in[12];
    const float* Wr1 = (const float*)d_in[13];
    const float* Wa  = (const float*)d_in[14];
    const float* ba  = (const float*)d_in[15];
    const float* Wb  = (const float*)d_in[16];
    const float* bb  = (const float*)d_in[17];
    const float* W1  = (const float*)d_in[18];
    const float* W2  = (const float*)d_in[19];
    const float* Wp1 = (const float*)d_in[20];
    const float* bp1 = (const float*)d_in[21];
    const float* Wp2 = (const float*)d_in[22];
    const float* bp2 = (const float*)d_in[23];
    const float* Wc1 = (const float*)d_in[24];
    const float* bc1 = (const float*)d_in[25];
    const float* Wc2 = (const float*)d_in[26];
    const float* bc2 = (const float*)d_in[27];

    const int E0 = in_sizes[2];
    const int E1 = in_sizes[4];

    float* out = (float*)d_out;              // [2000,2] logits + [1] loss
    float* ws  = (float*)d_ws;
    int*   iws = (int*)d_ws;
    ushort* uws = (ushort*)((char*)d_ws + FEND * sizeof(float));

    auto cdiv = [](int a, int b) { return (a + b - 1) / b; };

    // 1. prep: zero + pack + conversions (tail-risk segments first)
    prep<<<13864, 256, 0, stream>>>(ppr, x, Wr0, Wl0, Wr1, Wl1, W1, W2,
                                    Wa, Wb, Wp1, Wp2, uws, iws, out + (long)N2 * 2);

    // 2-4. CSR build, both layers (input-only)
    hist_both<<<cdiv(E0 + E1, 256), 256, 0, stream>>>(
        dst0, dst1, iws + ZCNT0, iws + ZCNT1, E0, E1);
    scan_both<<<2, 256, 0, stream>>>(iws + ZCNT0, iws + OFF0, iws + CUR0,
                                     iws + ZCNT1, iws + OFF1, iws + CUR1);
    fill_both<<<cdiv(E0 + E1, 256), 256, 0, stream>>>(
        src0, dst0, src1, dst1, iws + CUR0, iws + CUR1,
        iws + EID0, iws + EID1, E0, E1);

    // 5-6. SAGE layer 0
    csr_agg0<<<8064, 256, 0, stream>>>(uws + U_XB, iws + EID0, iws + OFF0,
                                       iws + ZCNT0, uws + U_A0);
    mfma128<<<dim3(2, 63), 256, 0, stream>>>(
        uws + U_A0, uws + U_WC0, ws + H1F, uws + U_A1, nullptr, bl0,
        1536, 1536, 1536, 256, 1024, 256, 2048, 0, 1536, 3);

    // 7-8. SAGE layer 1
    csr_agg1<<<2048, 256, 0, stream>>>(ws + H1F, iws + EID1, iws + OFF1,
                                       iws + ZCNT1, uws + U_A1);
    mfma128<<<dim3(2, 16), 256, 0, stream>>>(
        uws + U_A1, uws + U_WC1, ws + H2F, nullptr, nullptr, bl1,
        1024, 1024, 1024, 256, 0, 0, 0, 0, 1024, 0);

    // 9. logsoftmax + l2n + splits
    logsm_l2n_split<<<N2, 256, 0, stream>>>(ws + H2F, uws + U_ESPL, uws + U_SPLT);

    // 10-11. divergence loss (atomic straight into out[4000])
    mfma128<<<dim3(4, 16), 256, 0, stream>>>(
        uws + U_ESPL, uws + U_BD, ws + DIVCF, nullptr, nullptr, nullptr,
        512, 512, 512, 512, 0, 0, 0, 0, 512, 0);
    div_rows<<<N2, 256, 0, stream>>>(ws + DIVCF, ws + DIVCF + 256,
                                     out + (long)N2 * 2, 512, 1.0f / N2);

    // 12-14. PPR: xp1 (split-K=4, K padded 8192) -> xpa (transposed store)
    mfma128<<<dim3(4, 16, 4), 256, 0, stream>>>(
        uws + U_PPRB, uws + U_XTB, ws + PART, nullptr, nullptr, nullptr,
        8192, 8192, 8192, 512, 0, 0, 0, 0, 2048, 0);
    reduce_split<<<4096, 256, 0, stream>>>(ws + PART, uws + U_XPS, 1048576L, 4);
    mfma128<<<dim3(4, 16), 256, 0, stream>>>(
        uws + U_XPS, uws + U_WAD, nullptr, nullptr, uws + U_XPATB, ba,
        1024, 1024, 1024, 0, 0, 0, 0, 2048, 1024, 5);

    // 15-17. xp2 (split-K=2) -> xpb
    mfma128<<<dim3(4, 16, 2), 256, 0, stream>>>(
        uws + U_PPR2B, uws + U_XPATB, ws + PART, nullptr, nullptr, nullptr,
        2048, 2048, 2048, 512, 0, 0, 0, 0, 1024, 0);
    reduce_split<<<4096, 256, 0, stream>>>(ws + PART, uws + U_XPS, 1048576L, 2);
    mfma128<<<dim3(2, 16), 256, 0, stream>>>(
        uws + U_XPS, uws + U_WBD, ws + XPBF, nullptr, nullptr, bb,
        1024, 1024, 1024, 256, 0, 0, 0, 0, 1024, 0);

    // 18. g2 split into stacked rows [2048..4096)
    l2n_split<<<N2, 256, 0, stream>>>(ws + XPBF, uws + U_SPLT, 2048);

    // 19-21. stacked proj + clf
    mfma128<<<dim3(2, 32), 256, 0, stream>>>(
        uws + U_SPLT, uws + U_WP1D, nullptr, uws + U_TSPL, nullptr, bp1,
        512, 512, 512, 0, 512, 256, 4096, 0, 512, 3);
    mfma128<<<dim3(2, 32), 256, 0, stream>>>(
        uws + U_TSPL, uws + U_WP2D, ws + PB2, nullptr, nullptr, bp2,
        512, 512, 512, 256, 0, 0, 0, 0, 512, 0);
    clf2<<<4096, 256, 0, stream>>>(ws + PB2, Wc1, bc1, Wc2, bc2, out);
}

// Round 5
// 729.397 us; speedup vs baseline: 1.1788x; 1.0436x over previous
//
#include <hip/hip_runtime.h>

// ============================================================================
// train_model_27925877358676 — round 9: launch-count & latency pass II.
//  (1) CSR(hist+scan+fill, 3 kernels) -> ELL bucket build, ONE kernel:
//      slot=atomicAdd(cnt,1); ell[d+N*slot]=src. cap 64 (~12 sigma).
//  (2) l2n_split merged into logsm kernel (rowcombo); div_rows merged into
//      clf2 (final_combo); clf dot parallelized 8-way (was 32 lanes serial).
//  (3) XCD-chunked bijective block swizzle (flags bit3) on 32/64-block
//      mfma128 launches: each XCD gets contiguous row-slab -> A-tile L2 reuse.
//  21 -> 17 dispatches. ws ≈ 181 MB (fp32 40.2 + bf16 141.0).
// ============================================================================

typedef unsigned short ushort;
typedef __attribute__((ext_vector_type(8))) short short8;     // 8 bf16
typedef __attribute__((ext_vector_type(4))) float float4v;    // 4 fp32 acc
typedef __attribute__((ext_vector_type(4))) float f32x4;
typedef __attribute__((ext_vector_type(2))) float f32x2;
typedef __attribute__((ext_vector_type(8))) unsigned short us8;
typedef __attribute__((ext_vector_type(4))) unsigned short us4;
typedef __attribute__((ext_vector_type(2))) unsigned short us2;

__device__ __forceinline__ ushort bf16_rne(float v) {
    unsigned u = __float_as_uint(v);
    u += 0x7fffu + ((u >> 16) & 1u);
    return (ushort)(u >> 16);
}
__device__ __forceinline__ float bf16_f32(ushort h) {
    return __uint_as_float((unsigned)h << 16);
}

// ---------------- workspace layout ----------------
// fp32/int region (element offsets)
constexpr long ZCNT0 = 0;          // int[8000] (zeroed in prep)
constexpr long ZCNT1 = 8000;       // int[2000]
constexpr long ELL0  = 10240;      // int[8000*64]
constexpr long ELL1  = 522240;     // int[2000*64]
constexpr long H1F   = 650240;     // f[8064*256]
constexpr long H2F   = 2714624;    // f[2048*256]
constexpr long DIVCF = 3238912;    // f[2048*512]
constexpr long XPBF  = 4287488;    // f[2048*256]
constexpr long PB2   = 4811776;    // f[4096*256]
constexpr long PART  = 5860352;    // f[4*2048*512] split-K partial slabs
constexpr long FEND  = 10054656;
// bf16 region (ushort offsets from uws)
constexpr long U_PPRB  = 0;         // [2048][8192] (pad cols/rows zero)
constexpr long U_PPR2B = 16777216;  // [2048][2048]
constexpr long U_XTB   = 20971520;  // [512][8192]  (node cols >=8000 zero)
constexpr long U_XPATB = 25165824;  // [512][2048]
constexpr long U_A0    = 26214400;  // [8064][1536] = [x | agg_hi | agg_lo]
constexpr long U_A1    = 38600704;  // [2048][1024] = [h1_hi|h1_lo|agg_hi|agg_lo]
constexpr long U_ESPL  = 40697856;  // [2048][512]  = [e_hi|e_lo]
constexpr long U_XPS   = 41746432;  // [2048][1024] = [hi|lo]
constexpr long U_SPLT  = 43843584;  // [4096][512]  = [g_hi|g_lo] stacked
constexpr long U_TSPL  = 45940736;  // [4096][512]  = [t_hi|t_lo]
constexpr long U_WC0   = 48037888;  // [256][1536] [Wr0|Wl0|Wl0]
constexpr long U_WC1   = 48431104;  // [256][1024] [Wr1|Wr1|Wl1|Wl1]
constexpr long U_BD    = 48693248;  // [512][512]  [[W1|W1];[W2|W2]]
constexpr long U_WAD   = 48955392;  // [512][1024] [Wa|Wa]
constexpr long U_WBD   = 49479680;  // [256][1024] [Wb|Wb]
constexpr long U_WP1D  = 49741824;  // [256][512]  [Wp1|Wp1]
constexpr long U_WP2D  = 49872896;  // [256][512]  [Wp2|Wp2]
constexpr long U_XB    = 50003968;  // [40000][512] bf16 copy of x (exact)
// end 70483968 ushorts = 141.0 MB

// ---------------------------------------------------------------------------
// mfma128: C = op(A[M,K] @ B[N,K]^T), bf16 in. BK=128 tile 128x128, LDS
// XOR-swizzle via pre-swizzled global source (linear global_load_lds dest).
// gridDim.z > 1 => split-K slab store to Cf + z*M*N. Else epilogue:
//   Cf fp32 (nullable); Cs bf16 (rows<msplit; flags&2 -> [hi|lo@+nsplit]
//   else plain); Ct bf16 transposed (flags&4).
// flags: bit0 relu, bit1 split-store, bit2 transposed-store,
//        bit3 XCD-chunked block swizzle (requires (gx*gy)%8==0).
// ---------------------------------------------------------------------------
__global__ __launch_bounds__(256) void mfma128(
    const ushort* __restrict__ A, const ushort* __restrict__ B,
    float* __restrict__ Cf, ushort* __restrict__ Cs, ushort* __restrict__ Ct,
    const float* __restrict__ bias, int K, int lda, int ldb, int ldc,
    int ldso, int nsplit, int msplit, int ldt, int kchunk, int flags)
{
    __shared__ ushort As[128 * 128];
    __shared__ ushort Bs[128 * 128];
    const int tid = threadIdx.x;
    const int lane = tid & 63, wave = tid >> 6;
    const int wm = (wave >> 1) * 64, wn = (wave & 1) * 64;
    const int lr = lane & 15, quad = lane >> 4;

    int bx = blockIdx.x, by = blockIdx.y;
    if (flags & 8) {
        int gx = gridDim.x;
        int nb = gx * gridDim.y;        // must be % 8 == 0
        int flat = by * gx + bx;
        int per = nb >> 3;
        int c = flat & 7, j = flat >> 3;
        int idx = c * per + j;          // XCD c -> contiguous chunk
        by = idx / gx; bx = idx % gx;
    }
    const int bm = by * 128, bn = bx * 128;
    const int kbeg = blockIdx.z * kchunk;
    int kend = kbeg + kchunk; if (kend > K) kend = K;

    float4v acc[4][4] = {{{0.f, 0.f, 0.f, 0.f}}};

    for (int k0 = kbeg; k0 < kend; k0 += 128) {
#pragma unroll
        for (int issue = 0; issue < 8; ++issue) {
            int c = issue * 256 + tid;           // 0..2047
            int r = c >> 4, p = c & 15;
            int kk = (p ^ (r & 15)) * 8;         // pre-swizzled source column
            const ushort* ga = A + (long)(bm + r) * lda + k0 + kk;
            const ushort* gb = B + (long)(bn + r) * ldb + k0 + kk;
            __builtin_amdgcn_global_load_lds(
                (const __attribute__((address_space(1))) unsigned int*)ga,
                (__attribute__((address_space(3))) unsigned int*)&As[c * 8], 16, 0, 0);
            __builtin_amdgcn_global_load_lds(
                (const __attribute__((address_space(1))) unsigned int*)gb,
                (__attribute__((address_space(3))) unsigned int*)&Bs[c * 8], 16, 0, 0);
        }
        __syncthreads();

#pragma unroll
        for (int s = 0; s < 4; ++s) {
            short8 af[4], bf[4];
#pragma unroll
            for (int i = 0; i < 4; ++i) {
                int ra = wm + i * 16 + lr;
                af[i] = *(const short8*)&As[ra * 128 + (((s * 4 + quad) ^ (ra & 15)) * 8)];
                int rb = wn + i * 16 + lr;
                bf[i] = *(const short8*)&Bs[rb * 128 + (((s * 4 + quad) ^ (rb & 15)) * 8)];
            }
#pragma unroll
            for (int i = 0; i < 4; ++i)
#pragma unroll
                for (int j = 0; j < 4; ++j)
                    acc[i][j] = __builtin_amdgcn_mfma_f32_16x16x32_bf16(
                        af[i], bf[j], acc[i][j], 0, 0, 0);
        }
        __syncthreads();
    }

    if (gridDim.z > 1) {
        float* Cz = Cf + (long)blockIdx.z * (long)(gridDim.x * 128) * (long)(gridDim.y * 128);
#pragma unroll
        for (int i = 0; i < 4; ++i) {
            int row0 = bm + wm + i * 16 + quad * 4;
#pragma unroll
            for (int j = 0; j < 4; ++j) {
                int col = bn + wn + j * 16 + lr;
#pragma unroll
                for (int r = 0; r < 4; ++r)
                    Cz[(long)(row0 + r) * ldc + col] = acc[i][j][r];
            }
        }
        return;
    }

#pragma unroll
    for (int i = 0; i < 4; ++i) {
        int row0 = bm + wm + i * 16 + quad * 4;
#pragma unroll
        for (int j = 0; j < 4; ++j) {
            int col = bn + wn + j * 16 + lr;
            float bv = bias ? bias[col] : 0.f;
            us4 tp;
#pragma unroll
            for (int r = 0; r < 4; ++r) {
                int row = row0 + r;
                float v = acc[i][j][r] + bv;
                if (flags & 1) v = fmaxf(v, 0.f);
                if (Cf) Cf[(long)row * ldc + col] = v;
                if (Cs && row < msplit) {
                    if (flags & 2) {
                        ushort h = bf16_rne(v);
                        Cs[(long)row * ldso + col] = h;
                        Cs[(long)row * ldso + nsplit + col] = bf16_rne(v - bf16_f32(h));
                    } else {
                        Cs[(long)row * ldso + col] = bf16_rne(v);
                    }
                }
                if (flags & 4) tp[r] = bf16_rne(v);
            }
            if (flags & 4)
                *(us4*)&Ct[(long)col * ldt + row0] = tp;
        }
    }
}

// sum S partial slabs of [2048][512] -> bf16 hi/lo split [2048][1024]
__global__ __launch_bounds__(256) void reduce_split(
    const float* __restrict__ part, ushort* __restrict__ outs, long n, int S)
{
    long i = (long)blockIdx.x * 256 + threadIdx.x;
    if (i >= n) return;
    float s = 0.f;
    for (int k = 0; k < S; ++k) s += part[(long)k * n + i];
    int r = (int)(i >> 9), c = (int)(i & 511);
    ushort h = bf16_rne(s);
    outs[(long)r * 1024 + c] = h;
    outs[(long)r * 1024 + 512 + c] = bf16_rne(s - bf16_f32(h));
}

// ---------------------------------------------------------------------------
// prep megakernel. Block ranges (tail-risk segments FIRST):
//  [0,40)           zero cnt0/cnt1 + out loss
//  [40,296)         pack weights: 8 sections x 32 blocks, x2-vectorized
//  [296,8488)       ppr: 4 blocks/row -> PPRB [2048][8192], PPR2B
//  [8488,12584)     transpose x 32x32 tiles -> XTB [512][8192]
//  [12584,13864)    x row pass: f32x4 -> XB us4 (all 40000 rows) + A0 cols
// ---------------------------------------------------------------------------
__global__ __launch_bounds__(256) void prep(
    const float* __restrict__ ppr, const float* __restrict__ x,
    const float* __restrict__ Wr0, const float* __restrict__ Wl0,
    const float* __restrict__ Wr1, const float* __restrict__ Wl1,
    const float* __restrict__ W1,  const float* __restrict__ W2,
    const float* __restrict__ Wa,  const float* __restrict__ Wb,
    const float* __restrict__ Wp1, const float* __restrict__ Wp2,
    ushort* __restrict__ uws, int* __restrict__ iws, float* __restrict__ outloss)
{
    __shared__ float tsm[32][33];
    int b = blockIdx.x, t = threadIdx.x;

    if (b < 40) {                           // ---- zero ----
        int idx = b * 256 + t;
        if (idx < 10000) iws[idx] = 0;
        if (idx == 10000) *outloss = 0.f;
        return;
    }
    if (b < 296) {                          // ---- pack weights ----
        int b2 = b - 40;
        int sec = b2 >> 5;
        const float *sa, *sb = nullptr; long dstoff; int N, KA, dA, KB = 0, dB = 0;
        switch (sec) {
            case 0: sa = Wr0; KA = 512; dA = 1; sb = Wl0; KB = 512; dB = 2;
                    dstoff = U_WC0; N = 256; break;
            case 1: sa = Wr1; KA = 256; dA = 2; sb = Wl1; KB = 256; dB = 2;
                    dstoff = U_WC1; N = 256; break;
            case 2: sa = W1;  KA = 256; dA = 2; dstoff = U_BD;          N = 256; break;
            case 3: sa = W2;  KA = 256; dA = 2; dstoff = U_BD + 131072; N = 256; break;
            case 4: sa = Wa;  KA = 512; dA = 2; dstoff = U_WAD;  N = 512; break;
            case 5: sa = Wb;  KA = 512; dA = 2; dstoff = U_WBD;  N = 256; break;
            case 6: sa = Wp1; KA = 256; dA = 2; dstoff = U_WP1D; N = 256; break;
            default: sa = Wp2; KA = 256; dA = 2; dstoff = U_WP2D; N = 256; break;
        }
        int kd = KA * dA + KB * dB;
        long totv = (long)N * kd / 2;
        for (long v = (long)(b2 & 31) * 256 + t; v < totv; v += 8192) {
            long idx = v * 2;
            int n = (int)(idx / kd), rem = (int)(idx % kd);
            f32x2 val;
            if (rem < KA * dA) {
                int sc = rem % KA;
                val = *(const f32x2*)&sa[(long)n * KA + sc];
            } else {
                int sc = (rem - KA * dA) % KB;
                val = *(const f32x2*)&sb[(long)n * KB + sc];
            }
            us2 o; o[0] = bf16_rne(val[0]); o[1] = bf16_rne(val[1]);
            *(us2*)&uws[dstoff + idx] = o;
        }
        return;
    }
    if (b < 8488) {                         // ---- ppr conversion ----
        int id = b - 296;
        int r = id >> 2, q = id & 3;        // row, col-quarter
        bool live = r < 2000;
        const float* row = ppr + (long)r * 8000;
        int cbeg = q * 2048;
#pragma unroll
        for (int pass = 0; pass < 2; ++pass) {
            int c = cbeg + pass * 1024 + t * 4;
            f32x4 v = {0.f, 0.f, 0.f, 0.f};
            if (live && c < 8000) v = *(const f32x4*)(row + c);
            us4 u;
            u[0] = bf16_rne(v[0]); u[1] = bf16_rne(v[1]);
            u[2] = bf16_rne(v[2]); u[3] = bf16_rne(v[3]);
            *(us4*)&uws[U_PPRB + (long)r * 8192 + c] = u;
            if (c < 2048) {
                us4 w = u;
                if (c >= 2000) { w[0] = 0; w[1] = 0; w[2] = 0; w[3] = 0; }
                *(us4*)&uws[U_PPR2B + (long)r * 2048 + c] = w;
            }
        }
        return;
    }
    if (b < 12584) {                        // ---- transpose x -> XTB ----
        int id = b - 8488;
        int c0 = (id & 15) * 32, r0 = (id >> 4) * 32;   // r0 in [0,8192)
        int tx = t & 31, ty = t >> 5;
#pragma unroll
        for (int k = 0; k < 32; k += 8) {
            int r = r0 + ty + k;
            tsm[ty + k][tx] = (r < 8000) ? x[(long)r * 512 + c0 + tx] : 0.f;
        }
        __syncthreads();
#pragma unroll
        for (int k = 0; k < 32; k += 8) {
            int c = c0 + ty + k;
            uws[U_XTB + (long)c * 8192 + r0 + tx] = bf16_rne(tsm[tx][ty + k]);
        }
        return;
    }
    {                                       // ---- x row pass -> XB + A0 ----
        long vi = (long)(b - 12584) * 256 + t;
        for (; vi < 5120000; vi += 327680) {
            long gidx = vi * 4;
            f32x4 v = *(const f32x4*)&x[gidx];
            us4 u;
            u[0] = bf16_rne(v[0]); u[1] = bf16_rne(v[1]);
            u[2] = bf16_rne(v[2]); u[3] = bf16_rne(v[3]);
            *(us4*)&uws[U_XB + gidx] = u;
            long row = gidx >> 9;
            if (row < 8064) {
                int col = (int)(gidx & 511);
                *(us4*)&uws[U_A0 + row * 1536 + col] = u;
            }
        }
    }
}

// ---------------------------------------------------------------------------
// ELL bucket build, both layers, ONE kernel (no scan/fill chain).
// slot order is atomic-arrival order: fp32 mean reorder ~ulp, under threshold.
// ---------------------------------------------------------------------------
__global__ __launch_bounds__(256) void ell_fill(
    const int* __restrict__ src0, const int* __restrict__ dst0,
    const int* __restrict__ src1, const int* __restrict__ dst1,
    int* __restrict__ cnt0, int* __restrict__ cnt1,
    int* __restrict__ ell0, int* __restrict__ ell1, int E0, int E1)
{
    int e = blockIdx.x * 256 + threadIdx.x;
    if (e < E0) {
        int d = dst0[e];
        int r = atomicAdd(&cnt0[d], 1);
        if (r < 64) ell0[d + 8000 * r] = src0[e];
    } else if (e < E0 + E1) {
        int e1 = e - E0;
        int d = dst1[e1];
        int r = atomicAdd(&cnt1[d], 1);
        if (r < 64) ell1[d + 2000 * r] = src1[e1];
    }
}

// ---------------------------------------------------------------------------
// layer-0 gather-mean from bf16 XB (exact), ELL layout: 4 waves split the
// slot list, us8 loads (full 1KB row per wave-instr), 4-slot batch, LDS
// cross-wave reduce. Writes A0 [hi|lo] cols [512..1536).
// ---------------------------------------------------------------------------
__global__ __launch_bounds__(256) void csr_agg0(
    const ushort* __restrict__ xb, const int* __restrict__ ell,
    const int* __restrict__ cnt, ushort* __restrict__ a0)
{
    __shared__ float part[4][512];
    int d = blockIdx.x, t = threadIdx.x;
    int w = t >> 6, lane = t & 63;
    int k = (d < 8000) ? min(cnt[d], 64) : 0;
    float s[8] = {0.f, 0.f, 0.f, 0.f, 0.f, 0.f, 0.f, 0.f};
    int co = lane * 8;
    int j = w;
    for (; j + 12 < k; j += 16) {
        int e0 = ell[d + 8000 * j],        e1 = ell[d + 8000 * (j + 4)];
        int e2 = ell[d + 8000 * (j + 8)],  e3 = ell[d + 8000 * (j + 12)];
        us8 v0 = *(const us8*)&xb[(long)e0 * 512 + co];
        us8 v1 = *(const us8*)&xb[(long)e1 * 512 + co];
        us8 v2 = *(const us8*)&xb[(long)e2 * 512 + co];
        us8 v3 = *(const us8*)&xb[(long)e3 * 512 + co];
#pragma unroll
        for (int q = 0; q < 8; ++q)
            s[q] += bf16_f32(v0[q]) + bf16_f32(v1[q]) +
                    bf16_f32(v2[q]) + bf16_f32(v3[q]);
    }
    for (; j < k; j += 4) {
        us8 v = *(const us8*)&xb[(long)ell[d + 8000 * j] * 512 + co];
#pragma unroll
        for (int q = 0; q < 8; ++q) s[q] += bf16_f32(v[q]);
    }
#pragma unroll
    for (int q = 0; q < 8; ++q) part[w][co + q] = s[q];
    __syncthreads();
    float inv = 1.f / fmaxf((float)k, 1.f);
    long ro = (long)d * 1536;
#pragma unroll
    for (int h = 0; h < 2; ++h) {
        int c = 2 * t + h;
        float a = (part[0][c] + part[1][c] + part[2][c] + part[3][c]) * inv;
        ushort hi = bf16_rne(a);
        a0[ro + 512 + c] = hi;
        a0[ro + 1024 + c] = bf16_rne(a - bf16_f32(hi));
    }
}

// layer-1 gather-mean from fp32 H1, ELL layout. Writes A1 [hi|lo].
__global__ __launch_bounds__(256) void csr_agg1(
    const float* __restrict__ h, const int* __restrict__ ell,
    const int* __restrict__ cnt, ushort* __restrict__ a1)
{
    __shared__ float part[4][256];
    int d = blockIdx.x, t = threadIdx.x;
    int w = t >> 6, lane = t & 63;
    int k = (d < 2000) ? min(cnt[d], 64) : 0;
    f32x4 s = {0.f, 0.f, 0.f, 0.f};
    int co = lane * 4;
    int j = w;
    for (; j + 12 < k; j += 16) {
        int e0 = ell[d + 2000 * j],        e1 = ell[d + 2000 * (j + 4)];
        int e2 = ell[d + 2000 * (j + 8)],  e3 = ell[d + 2000 * (j + 12)];
        f32x4 v0 = *(const f32x4*)&h[(long)e0 * 256 + co];
        f32x4 v1 = *(const f32x4*)&h[(long)e1 * 256 + co];
        f32x4 v2 = *(const f32x4*)&h[(long)e2 * 256 + co];
        f32x4 v3 = *(const f32x4*)&h[(long)e3 * 256 + co];
        s += v0; s += v1; s += v2; s += v3;
    }
    for (; j < k; j += 4)
        s += *(const f32x4*)&h[(long)ell[d + 2000 * j] * 256 + co];
#pragma unroll
    for (int q = 0; q < 4; ++q) part[w][co + q] = s[q];
    __syncthreads();
    float inv = 1.f / fmaxf((float)k, 1.f);
    float a = (part[0][t] + part[1][t] + part[2][t] + part[3][t]) * inv;
    ushort hi = bf16_rne(a);
    long ro = (long)d * 1024;
    a1[ro + 512 + t] = hi;
    a1[ro + 768 + t] = bf16_rne(a - bf16_f32(hi));
}

// ---------------------------------------------------------------------------
// rowcombo: blocks [0,2000) logsoftmax+l2n+split on H2 -> ESPL, SPLT[0:2048);
//           blocks [2000,4000) l2n+split on XPBF -> SPLT rows [2048..).
// ---------------------------------------------------------------------------
__global__ __launch_bounds__(256) void rowcombo(
    const float* __restrict__ h2, const float* __restrict__ xpb,
    ushort* __restrict__ espl, ushort* __restrict__ splt)
{
    __shared__ float red[256];
    int b = blockIdx.x, t = threadIdx.x;
    if (b < 2000) {
        int i = b;
        float v = h2[(long)i * 256 + t];
        red[t] = v;
        __syncthreads();
        for (int s = 128; s > 0; s >>= 1) {
            if (t < s) red[t] = fmaxf(red[t], red[t + s]);
            __syncthreads();
        }
        float m = red[0];
        __syncthreads();
        float e = expf(v - m);
        red[t] = e;
        __syncthreads();
        for (int s = 128; s > 0; s >>= 1) {
            if (t < s) red[t] += red[t + s];
            __syncthreads();
        }
        float eb = v - (m + logf(red[0]));
        ushort hh = bf16_rne(eb);
        espl[(long)i * 512 + t] = hh;
        espl[(long)i * 512 + 256 + t] = bf16_rne(eb - bf16_f32(hh));
        __syncthreads();
        red[t] = eb * eb;
        __syncthreads();
        for (int s = 128; s > 0; s >>= 1) {
            if (t < s) red[t] += red[t + s];
            __syncthreads();
        }
        float g = eb / fmaxf(sqrtf(red[0]), 1e-12f);
        ushort gh = bf16_rne(g);
        splt[(long)i * 512 + t] = gh;
        splt[(long)i * 512 + 256 + t] = bf16_rne(g - bf16_f32(gh));
    } else {
        int i = b - 2000;
        float v = xpb[(long)i * 256 + t];
        red[t] = v * v;
        __syncthreads();
        for (int s = 128; s > 0; s >>= 1) {
            if (t < s) red[t] += red[t + s];
            __syncthreads();
        }
        float g = v / fmaxf(sqrtf(red[0]), 1e-12f);
        ushort gh = bf16_rne(g);
        long ro = (long)(2048 + i) * 512;
        splt[ro + t] = gh;
        splt[ro + 256 + t] = bf16_rne(g - bf16_f32(gh));
    }
}

// ---------------------------------------------------------------------------
// final_combo: blocks [0,4096) clf (8-way parallel dot) -> out logits;
//              blocks [4096,6096) div_rows -> atomicAdd out loss.
// ---------------------------------------------------------------------------
__global__ __launch_bounds__(256) void final_combo(
    const float* __restrict__ p, const float* __restrict__ Wc1,
    const float* __restrict__ bc1, const float* __restrict__ Wc2,
    const float* __restrict__ bc2, float* __restrict__ out,
    const float* __restrict__ divc, float scale)
{
    __shared__ float v[256];
    __shared__ float ps[8][33];
    __shared__ float hsum[32];
    __shared__ float r2[256];
    int b = blockIdx.x, t = threadIdx.x;
    if (b >= 4096) {
        // ---- div_rows: row i of DIVC [2048][512], o1=cols<256, o2=cols>=256
        int i = b - 4096;
        float a = divc[(long)i * 512 + t], bb = divc[(long)i * 512 + 256 + t];
        v[t] = a * a;
        r2[t] = bb * bb;
        __syncthreads();
        for (int s = 128; s > 0; s >>= 1) {
            if (t < s) { v[t] += v[t + s]; r2[t] += r2[t + s]; }
            __syncthreads();
        }
        float na = fmaxf(sqrtf(v[0]), 1e-12f);
        float nb = fmaxf(sqrtf(r2[0]), 1e-12f);
        __syncthreads();
        float d = a / na - bb / nb;
        v[t] = d * d;
        __syncthreads();
        for (int s = 128; s > 0; s >>= 1) {
            if (t < s) v[t] += v[t + s];
            __syncthreads();
        }
        if (t == 0) atomicAdd(&out[4000], v[0] * scale);
        return;
    }
    int half = b >> 11, i = b & 2047;
    if (i >= 2000) return;
    v[t] = p[(long)b * 256 + t];
    __syncthreads();
    int o = t & 31, ch = t >> 5;
    const float* w = Wc1 + (long)o * 256 + ch * 32;
    const float* vv = v + ch * 32;
    float s = 0.f;
#pragma unroll
    for (int k2 = 0; k2 < 32; ++k2) s += vv[k2] * w[k2];
    ps[ch][o] = s;
    __syncthreads();
    if (t < 32) {
        float a = bc1[t];
#pragma unroll
        for (int c = 0; c < 8; ++c) a += ps[c][t];
        a = fmaxf(a, 0.f);
        hsum[t] = a * Wc2[t];
    }
    __syncthreads();
    if (t == 0) {
        float s2 = bc2[0];
        for (int k2 = 0; k2 < 32; ++k2) s2 += hsum[k2];
        out[(long)i * 2 + half] = s2;
    }
}

// ---------------------------------------------------------------------------
extern "C" void kernel_launch(void* const* d_in, const int* in_sizes, int n_in,
                              void* d_out, int out_size, void* d_ws, size_t ws_size,
                              hipStream_t stream)
{
    constexpr int N2 = 2000;

    const float* x   = (const float*)d_in[0];
    const float* ppr = (const float*)d_in[1];
    const int* src0  = (const int*)d_in[2];
    const int* dst0  = (const int*)d_in[3];
    const int* src1  = (const int*)d_in[4];
    const int* dst1  = (const int*)d_in[5];
    const float* Wl0 = (const float*)d_in[8];
    const float* bl0 = (const float*)d_in[9];
    const float* Wr0 = (const float*)d_in[10];
    const float* Wl1 = (const float*)d_in[11];
    const float* bl1 = (const float*)d_in[12];
    const float* Wr1 = (const float*)d_in[13];
    const float* Wa  = (const float*)d_in[14];
    const float* ba  = (const float*)d_in[15];
    const float* Wb  = (const float*)d_in[16];
    const float* bb  = (const float*)d_in[17];
    const float* W1  = (const float*)d_in[18];
    const float* W2  = (const float*)d_in[19];
    const float* Wp1 = (const float*)d_in[20];
    const float* bp1 = (const float*)d_in[21];
    const float* Wp2 = (const float*)d_in[22];
    const float* bp2 = (const float*)d_in[23];
    const float* Wc1 = (const float*)d_in[24];
    const float* bc1 = (const float*)d_in[25];
    const float* Wc2 = (const float*)d_in[26];
    const float* bc2 = (const float*)d_in[27];

    const int E0 = in_sizes[2];
    const int E1 = in_sizes[4];

    float* out = (float*)d_out;              // [2000,2] logits + [1] loss
    float* ws  = (float*)d_ws;
    int*   iws = (int*)d_ws;
    ushort* uws = (ushort*)((char*)d_ws + FEND * sizeof(float));

    auto cdiv = [](int a, int b) { return (a + b - 1) / b; };

    // 1. prep: zero + pack + conversions
    prep<<<13864, 256, 0, stream>>>(ppr, x, Wr0, Wl0, Wr1, Wl1, W1, W2,
                                    Wa, Wb, Wp1, Wp2, uws, iws, out + (long)N2 * 2);

    // 2. ELL bucket build, both layers, one kernel
    ell_fill<<<cdiv(E0 + E1, 256), 256, 0, stream>>>(
        src0, dst0, src1, dst1, iws + ZCNT0, iws + ZCNT1,
        iws + ELL0, iws + ELL1, E0, E1);

    // 3-4. SAGE layer 0
    csr_agg0<<<8064, 256, 0, stream>>>(uws + U_XB, iws + ELL0, iws + ZCNT0,
                                       uws + U_A0);
    mfma128<<<dim3(2, 63), 256, 0, stream>>>(
        uws + U_A0, uws + U_WC0, ws + H1F, uws + U_A1, nullptr, bl0,
        1536, 1536, 1536, 256, 1024, 256, 2048, 0, 1536, 3);

    // 5-6. SAGE layer 1
    csr_agg1<<<2048, 256, 0, stream>>>(ws + H1F, iws + ELL1, iws + ZCNT1,
                                       uws + U_A1);
    mfma128<<<dim3(2, 16), 256, 0, stream>>>(
        uws + U_A1, uws + U_WC1, ws + H2F, nullptr, nullptr, bl1,
        1024, 1024, 1024, 256, 0, 0, 0, 0, 1024, 8);

    // 7-9. PPR: xp1 (split-K=4, K padded 8192) -> xpa (transposed store)
    mfma128<<<dim3(4, 16, 4), 256, 0, stream>>>(
        uws + U_PPRB, uws + U_XTB, ws + PART, nullptr, nullptr, nullptr,
        8192, 8192, 8192, 512, 0, 0, 0, 0, 2048, 8);
    reduce_split<<<4096, 256, 0, stream>>>(ws + PART, uws + U_XPS, 1048576L, 4);
    mfma128<<<dim3(4, 16), 256, 0, stream>>>(
        uws + U_XPS, uws + U_WAD, nullptr, nullptr, uws + U_XPATB, ba,
        1024, 1024, 1024, 0, 0, 0, 0, 2048, 1024, 13);

    // 10-12. xp2 (split-K=2) -> xpb
    mfma128<<<dim3(4, 16, 2), 256, 0, stream>>>(
        uws + U_PPR2B, uws + U_XPATB, ws + PART, nullptr, nullptr, nullptr,
        2048, 2048, 2048, 512, 0, 0, 0, 0, 1024, 8);
    reduce_split<<<4096, 256, 0, stream>>>(ws + PART, uws + U_XPS, 1048576L, 2);
    mfma128<<<dim3(2, 16), 256, 0, stream>>>(
        uws + U_XPS, uws + U_WBD, ws + XPBF, nullptr, nullptr, bb,
        1024, 1024, 1024, 256, 0, 0, 0, 0, 1024, 8);

    // 13. rowwise combo: logsm+l2n(H2) -> ESPL,SPLT[0:2048); l2n(XPBF) -> [2048:)
    rowcombo<<<4000, 256, 0, stream>>>(ws + H2F, ws + XPBF,
                                       uws + U_ESPL, uws + U_SPLT);

    // 14. divergence GEMM
    mfma128<<<dim3(4, 16), 256, 0, stream>>>(
        uws + U_ESPL, uws + U_BD, ws + DIVCF, nullptr, nullptr, nullptr,
        512, 512, 512, 512, 0, 0, 0, 0, 512, 8);

    // 15-16. stacked proj
    mfma128<<<dim3(2, 32), 256, 0, stream>>>(
        uws + U_SPLT, uws + U_WP1D, nullptr, uws + U_TSPL, nullptr, bp1,
        512, 512, 512, 0, 512, 256, 4096, 0, 512, 11);
    mfma128<<<dim3(2, 32), 256, 0, stream>>>(
        uws + U_TSPL, uws + U_WP2D, ws + PB2, nullptr, nullptr, bp2,
        512, 512, 512, 256, 0, 0, 0, 0, 512, 8);

    // 17. clf + div_rows combo -> out
    final_combo<<<6096, 256, 0, stream>>>(ws + PB2, Wc1, bc1, Wc2, bc2, out,
                                          ws + DIVCF, 1.0f / N2);
}